// Round 19
// baseline (205.808 us; speedup 1.0000x reference)
//
#include <hip/hip_runtime.h>
#include <math.h>

#define KORD 3
#ifndef M_PI
#define M_PI 3.14159265358979323846
#endif

typedef __attribute__((ext_vector_type(8))) __bf16 bf16x8;
typedef __attribute__((ext_vector_type(4))) float  f32x4;

__device__ __forceinline__ float leaky_(float v){ return v >= 0.f ? v : 0.01f*v; }

__device__ __forceinline__ float tanh_fast(float x){
  float xc = fminf(fmaxf(x, -10.f), 10.f);
  float t = __expf(2.f*xc);
  return (t - 1.f) * __builtin_amdgcn_rcpf(t + 1.f);
}

__device__ __forceinline__ f32x4 mfma16(bf16x8 a, bf16x8 b, f32x4 c){
  return __builtin_amdgcn_mfma_f32_16x16x32_bf16(a, b, c, 0, 0, 0);
}

// direct global->LDS DMA, 16B per lane (lds dest = wave-uniform base + lane*16)
__device__ __forceinline__ void gll16(const __bf16* g, __bf16* l){
  __builtin_amdgcn_global_load_lds(
      (__attribute__((address_space(1))) void*)(g),
      (__attribute__((address_space(3))) void*)(l), 16, 0, 0);
}

// ---------------- Chebyshev coefficients (flush |c|<1e-6 to exact 0) ----------------
__global__ void k_coe(const float* __restrict__ temp, float* __restrict__ coe){
  if (threadIdx.x == 0 && blockIdx.x == 0){
    for (int i = 0; i <= KORD; ++i){
      float acc = 0.f;
      for (int j = 0; j <= KORD; ++j){
        double th = ((double)(KORD - j) + 0.5) * M_PI / (double)(KORD + 1);
        float t = temp[j]; t = t > 0.f ? t : 0.f;
        acc += t * (float)cos((double)i * th);
      }
      acc *= 2.f / (float)(KORD + 1);
      if (i >= 1 && fabsf(acc) < 1e-6f) acc = 0.f;
      coe[i] = acc;
    }
  }
}

// ---------------- f32 -> bf16 convert ----------------
__global__ __launch_bounds__(256) void k_cvt(const float* __restrict__ in,
                                             __bf16* __restrict__ out, int n){
  int i = blockIdx.x*256 + threadIdx.x;
  if (i < n) out[i] = (__bf16)in[i];
}

// ---------------- f32 -> bf16 convert with per-64-col XOR swizzle ----------------
__global__ __launch_bounds__(256) void k_cvt_swz(const float* __restrict__ in,
                                                 __bf16* __restrict__ out){
  int i = blockIdx.x*256 + threadIdx.x;
  int r = i >> 9, c = i & 511;
  out[(size_t)r*512 + (c ^ ((r & 7) << 3))] = (__bf16)in[i];
}

// ---------------- W1t[e][d] = W1[d][e] (bf16) ----------------
__global__ __launch_bounds__(256) void k_w1t(const float* __restrict__ W1,
                                             __bf16* __restrict__ W1t){
  int t = threadIdx.x;
  for (int i = 0; i < 16; ++i){
    int e4 = i*256 + t;
    int e = e4 >> 6, d = e4 & 63;
    W1t[e*64 + d] = (__bf16)W1[d*64 + e];
  }
}

// ---------------- Wlt[o][k] = Wl[k][o] (bf16), Wl: [32768][128] ----------------
__global__ __launch_bounds__(256) void k_wlt(const float* __restrict__ Wl,
                                             __bf16* __restrict__ Wlt){
  __shared__ float Ls[64][65];
  int k0 = blockIdx.x*64, o0 = blockIdx.y*64;
  int t = threadIdx.x;
  for (int i = 0; i < 16; ++i){
    int e = i*256 + t; int r = e >> 6, c = e & 63;
    Ls[r][c] = Wl[(size_t)(k0 + r)*128 + o0 + c];
  }
  __syncthreads();
  for (int i = 0; i < 16; ++i){
    int e = i*256 + t; int r = e >> 6, c = e & 63;
    Wlt[(size_t)(o0 + r)*32768 + k0 + c] = (__bf16)Ls[c][r];
  }
}

// ---------------- bsaTb[c][m] = bf16(bsa[m][c]) ----------------
__global__ __launch_bounds__(256) void k_bsat(const float* __restrict__ bsa,
                                              __bf16* __restrict__ bsaTb){
  __shared__ float Ls[64][65];
  int n0 = blockIdx.x*64, m0 = blockIdx.y*64;
  int t = threadIdx.x;
  for (int i = 0; i < 16; ++i){
    int e = i*256 + t; int r = e >> 6, c = e & 63;
    Ls[r][c] = bsa[(size_t)(n0 + r)*512 + m0 + c];
  }
  __syncthreads();
  for (int i = 0; i < 16; ++i){
    int e = i*256 + t; int r = e >> 6, c = e & 63;
    bsaTb[(size_t)(m0 + r)*512 + n0 + c] = (__bf16)Ls[c][r];
  }
}

// ---------------- embed both layouts: Ht[j][n] and Hnd[cs][n][d] ----------------
__global__ __launch_bounds__(256) void k_embed2(const float* __restrict__ x,
    const float* __restrict__ Wp, const float* __restrict__ bp,
    __bf16* __restrict__ Ht, __bf16* __restrict__ Hnd){
  __shared__ float Ls[64][65];
  int cs = blockIdx.x, n0 = blockIdx.y*64;
  int t = threadIdx.x;
  for (int i = 0; i < 16; ++i){
    int e = i*256 + t; int d = e >> 6, nn = e & 63;
    float v = x[cs*512 + n0 + nn]*Wp[d] + bp[d];
    Ls[d][nn] = v;
    Ht[(size_t)(cs*64 + d)*512 + n0 + nn] = (__bf16)v;
  }
  __syncthreads();
  for (int i = 0; i < 16; ++i){
    int e = i*256 + t; int nn = e >> 6, d = e & 63;
    Hnd[((size_t)cs*512 + n0 + nn)*64 + d] = (__bf16)Ls[d][nn];
  }
}

// ---------------- combo: Gnd[cs][n][d] = cheby-combo + SXnd (zero-coe terms skipped) ----------------
__global__ __launch_bounds__(256) void k_combo(const __bf16* __restrict__ Ht,
    const __bf16* __restrict__ T1t, const __bf16* __restrict__ T2t,
    const __bf16* __restrict__ T3t, const __bf16* __restrict__ SXnd,
    const float* __restrict__ coe, __bf16* __restrict__ Gnd){
  __shared__ float Ls[64][65];
  int cs = blockIdx.x, n0 = blockIdx.y*64;
  int t = threadIdx.x;
  float c0 = coe[0]*0.5f, c1 = coe[1], c2 = coe[2], c3 = coe[3];
  for (int i = 0; i < 16; ++i){
    int e = i*256 + t; int d = e >> 6, nn = e & 63;
    size_t idx = (size_t)(cs*64 + d)*512 + n0 + nn;
    float v = c0*(float)Ht[idx];
    if (c1 != 0.f) v += c1*(float)T1t[idx];
    if (c2 != 0.f) v += c2*(float)T2t[idx];
    if (c3 != 0.f) v += c3*(float)T3t[idx];
    Ls[d][nn] = v;
  }
  __syncthreads();
  for (int i = 0; i < 16; ++i){
    int e = i*256 + t; int nn = e >> 6, d = e & 63;
    size_t oidx = ((size_t)cs*512 + n0 + nn)*64 + d;
    Gnd[oidx] = (__bf16)(Ls[d][nn] + (float)SXnd[oidx]);
  }
}

// ---------------- MFMA GEMM: C[z] = A[z] * B[z]^T (+epilogue) ----------------
// EPI: 0 bf16 out; 1 bf16 2v-Z; 2 bf16 tanh_fast(v+Eb16[row*512+col]) REPACK + col-swizzle;
//      3 f32 out; 5 bf16 leaky(v+Ef[col])
template<int BM, int BN, int WM, int WN, int EPI, bool SWZ>
__global__ __launch_bounds__(256) void gbt(
    const __bf16* __restrict__ A, size_t aB, int lda,
    const __bf16* __restrict__ B, size_t bB, int ldb,
    const void*  __restrict__ E, size_t eB,
    void* __restrict__ C, size_t cB, int ldc, int K, int gx, int gy,
    const float* __restrict__ gate, int gateCnt){
  if (gate){
    bool anyNZ = false;
    for (int i = 0; i < gateCnt; ++i) anyNZ |= (gate[i] != 0.f);
    if (!anyNZ) return;
  }
  constexpr int WTM = BM/WM, WTN = BN/WN;
  constexpr int FM = WTM/16, FN = WTN/16;
  constexpr int LDK = 72;
  constexpr bool RPK = (EPI == 2 && BM == 128 && BN == 128);
  __shared__ __bf16 SMEM[BM*LDK + BN*LDK];
  __bf16* As = SMEM;
  __bf16* Bs = SMEM + BM*LDK;
  const int tid = threadIdx.x;
  const int wave = tid >> 6, lane = tid & 63;
  const int wm = wave % WM, wn = wave / WM;
  int bx, by, bz;
  if (SWZ){
    int id = blockIdx.x;
    int xcd = id & 7, j = id >> 3;
    int tiles = gx*gy;
    int tile = j % tiles, sin = j / tiles;
    bz = xcd + 8*sin; bx = tile % gx; by = tile / gx;
  } else { bx = blockIdx.x; by = blockIdx.y; bz = blockIdx.z; }
  const int m0 = bx*BM, n0 = by*BN;
  const __bf16* Ab = A + (size_t)bz*aB + (size_t)m0*lda;
  const __bf16* Bb = B + (size_t)bz*bB + (size_t)n0*ldb;
  f32x4 acc[FM][FN] = {};
  for (int k0 = 0; k0 < K; k0 += 64){
    __syncthreads();
    constexpr int AIT = BM*64/(256*8);
#pragma unroll
    for (int i = 0; i < AIT; ++i){
      int e = i*256 + tid; int r = e >> 3, c = (e & 7)*8;
      *(float4*)&As[r*LDK + c] = *(const float4*)&Ab[(size_t)r*lda + k0 + c];
    }
    constexpr int BIT = BN*64/(256*8);
#pragma unroll
    for (int i = 0; i < BIT; ++i){
      int e = i*256 + tid; int r = e >> 3, c = (e & 7)*8;
      *(float4*)&Bs[r*LDK + c] = *(const float4*)&Bb[(size_t)r*ldb + k0 + c];
    }
    __syncthreads();
#pragma unroll
    for (int ks = 0; ks < 2; ++ks){
      bf16x8 af[FM], bfr[FN];
      const int ko = ks*32 + (lane >> 4)*8;
#pragma unroll
      for (int i = 0; i < FM; ++i)
        af[i] = *(const bf16x8*)&As[(wm*WTM + i*16 + (lane & 15))*LDK + ko];
#pragma unroll
      for (int j = 0; j < FN; ++j)
        bfr[j] = *(const bf16x8*)&Bs[(wn*WTN + j*16 + (lane & 15))*LDK + ko];
#pragma unroll
      for (int i = 0; i < FM; ++i)
#pragma unroll
        for (int j = 0; j < FN; ++j)
          acc[i][j] = mfma16(af[i], bfr[j], acc[i][j]);
    }
  }
  const int lr = (lane >> 4)*4, lc = lane & 15;
  __bf16* Cb = (__bf16*)C + (size_t)bz*cB;
  if constexpr (RPK){
    const __bf16* Eb = (const __bf16*)E;
    __syncthreads();
    __bf16* R = SMEM;  // 128*136*2B = 34816
#pragma unroll
    for (int i = 0; i < FM; ++i)
#pragma unroll
      for (int j = 0; j < FN; ++j)
#pragma unroll
        for (int r = 0; r < 4; ++r){
          int row = wm*64 + i*16 + lr + r;
          int col = wn*64 + j*16 + lc;
          float v = tanh_fast(acc[i][j][r] + (float)Eb[(size_t)(m0 + row)*512 + (n0 + col)]);
          R[row*136 + col] = (__bf16)v;
        }
    __syncthreads();
#pragma unroll
    for (int it = 0; it < 8; ++it){
      int q = it*256 + tid; int row = q >> 4, ch = q & 15;
      *(bf16x8*)&Cb[(size_t)(m0 + row)*ldc + (n0 + ((ch*8) ^ ((row & 7) << 3)))] =
          *(const bf16x8*)&R[row*136 + ch*8];
    }
    return;
  }
  float*  Cf = (float*)C  + (size_t)bz*cB;
  const __bf16* Zb = (const __bf16*)E + (size_t)bz*eB;
  const float*  Ef = (const float*)E;
  const __bf16* Eb = (const __bf16*)E;
#pragma unroll
  for (int i = 0; i < FM; ++i){
    int row = m0 + wm*WTM + i*16 + lr;
#pragma unroll
    for (int j = 0; j < FN; ++j){
      int col = n0 + wn*WTN + j*16 + lc;
#pragma unroll
      for (int r = 0; r < 4; ++r){
        float v = acc[i][j][r];
        size_t idx = (size_t)(row + r)*ldc + col;
        if (EPI == 0){ Cb[idx] = (__bf16)v; }
        else if (EPI == 1){ Cb[idx] = (__bf16)(2.f*v - (float)Zb[idx]); }
        else if (EPI == 2){ Cb[(size_t)(row + r)*ldc + (col ^ (((row + r) & 7) << 3))] =
                              (__bf16)tanh_fast(v + (float)Eb[(size_t)(row + r)*512 + col]); }
        else if (EPI == 3){ Cf[idx] = v; }
        else if (EPI == 5){ float tt = v + Ef[col]; Cb[idx] = (__bf16)(tt >= 0.f ? tt : 0.01f*tt); }
      }
    }
  }
}

// ---------------- flash v8: 4-buffer gload_lds, 3 stages in flight, vmcnt(8) ----------------
// Vsab/Pt col-swizzled; Ht plain (PV h-frags loaded to regs per c0).
template<bool SWZ>
__global__ __launch_bounds__(256) void k_flash(
    const __bf16* __restrict__ Vsab,  // [512][512] swizzled
    const __bf16* __restrict__ Pt,    // [z][512(c)][512(m)] swizzled
    const __bf16* __restrict__ Ht,    // [z*64(d)][512(m)] plain
    __bf16* __restrict__ SXnd){       // [z][512(n')][64(d)]
  __shared__ __bf16 VaL[4][4096];     // [64][64] linear, quad
  __shared__ __bf16 PbL[4][4096];
  __shared__ __bf16 Ps[64*72];
  __shared__ float rs2[2][64];
  const int tid = threadIdx.x, wave = tid >> 6, lane = tid & 63;
  const int wm = wave & 1, wn = wave >> 1;
  const int lr = (lane >> 4)*4, lc = lane & 15;
  int np0, z;
  if (SWZ){
    int id = blockIdx.x;
    int xcd = id & 7, j = id >> 3;
    int tile = j & 7, sin = j >> 3;
    z = xcd + 8*sin; np0 = tile*64;
  } else { np0 = blockIdx.x*64; z = blockIdx.y; }
  const __bf16* Vb = Vsab + (size_t)np0*512;
  const __bf16* Pz = Pt + (size_t)z*262144;
  const __bf16* Hz = Ht + (size_t)z*32768;
  const int srow = lane >> 3;
  const int scol = (lane & 7)*8;
  auto stageVP = [&](int buf, int c0, int k0){
#pragma unroll
    for (int rr = 0; rr < 2; ++rr){
      int rb = (rr*4 + wave)*8;
      gll16(Vb + (size_t)(rb + srow)*512 + k0 + scol, &VaL[buf][(rr*4 + wave)*512]);
      gll16(Pz + (size_t)(c0 + rb + srow)*512 + k0 + scol, &PbL[buf][(rr*4 + wave)*512]);
    }
  };
  const int kx = (lc & 7) << 3;
  f32x4 acc_sx[2][2] = {};
  float rowp[8] = {};
  // prologue: 3 tiles in flight
  stageVP(0, 0, 0);
  stageVP(1, 0, 64);
  stageVP(2, 0, 128);
  for (int c0i = 0; c0i < 8; ++c0i){
    const int c0 = c0i*64;
    f32x4 acc_s[2][2] = {};
#pragma unroll
    for (int k0i = 0; k0i < 8; ++k0i){
      // wait: tile t=c0i*8+k0i landed when outstanding <= 4*(stages in flight beyond t)
      if (c0i == 7 && k0i >= 6){
        if (k0i == 6) asm volatile("s_waitcnt vmcnt(4)" ::: "memory");
        else          asm volatile("s_waitcnt vmcnt(0)" ::: "memory");
      } else {
        asm volatile("s_waitcnt vmcnt(8)" ::: "memory");
      }
      __builtin_amdgcn_s_barrier();
      // issue-early: stage tile t+3 (its buffer was consumed at iter t-1; barrier proves done)
      {
        int nt = c0i*8 + k0i + 3;
        if (nt < 64) stageVP((k0i + 3) & 3, (nt >> 3) << 6, (nt & 7) << 6);
      }
      const __bf16* Vc = VaL[k0i & 3];
      const __bf16* Pc = PbL[k0i & 3];
#pragma unroll
      for (int ks = 0; ks < 2; ++ks){
        const int kox = (ks*32 + (lane >> 4)*8) ^ kx;
        bf16x8 a0 = *(const bf16x8*)&Vc[(wm*32 +  0 + lc)*64 + kox];
        bf16x8 a1 = *(const bf16x8*)&Vc[(wm*32 + 16 + lc)*64 + kox];
        bf16x8 b0 = *(const bf16x8*)&Pc[(wn*32 +  0 + lc)*64 + kox];
        bf16x8 b1 = *(const bf16x8*)&Pc[(wn*32 + 16 + lc)*64 + kox];
        acc_s[0][0] = mfma16(a0, b0, acc_s[0][0]);
        acc_s[0][1] = mfma16(a0, b1, acc_s[0][1]);
        acc_s[1][0] = mfma16(a1, b0, acc_s[1][0]);
        acc_s[1][1] = mfma16(a1, b1, acc_s[1][1]);
      }
    }
    // ---- epilogue for this c0 ----
    // exp + rowsum partials -> Ps
#pragma unroll
    for (int i = 0; i < 2; ++i)
#pragma unroll
      for (int j = 0; j < 2; ++j)
#pragma unroll
        for (int rr = 0; rr < 4; ++rr){
          float e = __expf(fminf(acc_s[i][j][rr], 30.f));
          rowp[i*4 + rr] += e;
          Ps[(wm*32 + i*16 + lr + rr)*72 + wn*32 + j*16 + lc] = (__bf16)e;
        }
    // h-fragments for PV straight from global (plain Ht)
    bf16x8 h0k[2], h1k[2];
#pragma unroll
    for (int ks = 0; ks < 2; ++ks){
      const int ko = ks*32 + (lane >> 4)*8;
      h0k[ks] = *(const bf16x8*)&Hz[(size_t)(wn*32 +  0 + lc)*512 + c0 + ko];
      h1k[ks] = *(const bf16x8*)&Hz[(size_t)(wn*32 + 16 + lc)*512 + c0 + ko];
    }
    asm volatile("s_waitcnt lgkmcnt(0)" ::: "memory");
    __builtin_amdgcn_s_barrier();
    // PV: acc_sx[n'][d] += expS @ h
#pragma unroll
    for (int ks = 0; ks < 2; ++ks){
      const int ko = ks*32 + (lane >> 4)*8;
      bf16x8 p0 = *(const bf16x8*)&Ps[(wm*32 +  0 + lc)*72 + ko];
      bf16x8 p1 = *(const bf16x8*)&Ps[(wm*32 + 16 + lc)*72 + ko];
      acc_sx[0][0] = mfma16(p0, h0k[ks], acc_sx[0][0]);
      acc_sx[0][1] = mfma16(p0, h1k[ks], acc_sx[0][1]);
      acc_sx[1][0] = mfma16(p1, h0k[ks], acc_sx[1][0]);
      acc_sx[1][1] = mfma16(p1, h1k[ks], acc_sx[1][1]);
    }
  }
  // rowsum reduce (16-lane groups), combine wn waves via LDS
#pragma unroll
  for (int s = 0; s < 8; ++s){
    float v = rowp[s];
    v += __shfl_xor(v, 1, 64); v += __shfl_xor(v, 2, 64);
    v += __shfl_xor(v, 4, 64); v += __shfl_xor(v, 8, 64);
    rowp[s] = v;
  }
  __syncthreads();
  if ((lane & 15) == 0){
#pragma unroll
    for (int i = 0; i < 2; ++i)
#pragma unroll
      for (int rr = 0; rr < 4; ++rr)
        rs2[wn][wm*32 + i*16 + lr + rr] = rowp[i*4 + rr];
  }
  __syncthreads();
#pragma unroll
  for (int i = 0; i < 2; ++i)
#pragma unroll
    for (int rr = 0; rr < 4; ++rr){
      int row = wm*32 + i*16 + lr + rr;
      float inv = __builtin_amdgcn_rcpf(rs2[0][row] + rs2[1][row]);
#pragma unroll
      for (int j = 0; j < 2; ++j){
        int col = wn*32 + j*16 + lc;
        SXnd[((size_t)z*512 + np0 + row)*64 + col] = (__bf16)(acc_sx[i][j][rr]*inv);
      }
    }
}

// ---------------- reduce 128 K-partials + bias + leaky ----------------
__global__ __launch_bounds__(256) void k_final2(
    const float* __restrict__ part, const float* __restrict__ bl,
    float* __restrict__ out){
  int idx = blockIdx.x*256 + threadIdx.x;
  int o = idx & 127;
  float acc = bl[o];
#pragma unroll 8
  for (int p = 0; p < 128; ++p) acc += part[(size_t)p*16384 + idx];
  out[idx] = leaky_(acc);
}

extern "C" void kernel_launch(void* const* d_in, const int* in_sizes, int n_in,
                              void* d_out, int out_size, void* d_ws, size_t ws_size,
                              hipStream_t stream){
  const float* x    = (const float*)d_in[0];
  const float* adj  = (const float*)d_in[1];
  const float* Wp   = (const float*)d_in[2];
  const float* bp   = (const float*)d_in[3];
  const float* Ksa  = (const float*)d_in[4];
  const float* Vsa  = (const float*)d_in[5];
  const float* bsa  = (const float*)d_in[6];
  const float* temp = (const float*)d_in[7];
  const float* W1   = (const float*)d_in[8];
  const float* b1   = (const float*)d_in[9];
  const float* Wl   = (const float*)d_in[10];
  const float* bl   = (const float*)d_in[11];
  float* out = (float*)d_out;

  // ---- workspace carve-up (bytes), chunk-adaptive ----
  char* ws = (char*)d_ws;
  size_t off = 0;
  auto alloc = [&](size_t bytes){ void* p = ws + off; off += (bytes + 255) & ~(size_t)255; return p; };
  float*  coe  = (float*)alloc(64);
  __bf16* G2b  = (__bf16*)alloc((size_t)128*32768*2);   // 8.4 MB
  __bf16* Wlt  = (__bf16*)alloc((size_t)128*32768*2);   // 8.4 MB
  float*  part = (float*)alloc((size_t)128*16384*4);    // 8.4 MB
  __bf16* bsaTb= (__bf16*)alloc((size_t)512*512*2);     // 0.5 MB bf16
  __bf16* adjb = (__bf16*)alloc((size_t)512*512*2);
  __bf16* Ksab = (__bf16*)alloc((size_t)512*512*2);
  __bf16* Vsab = (__bf16*)alloc((size_t)512*512*2);
  __bf16* W1t  = (__bf16*)alloc((size_t)64*64*2);
  const size_t fixedOff = off;

  // per-slice: 8 bf16 [64x512]-sized bufs (64KB each) + Pt (512KB)
  int CH = 128;
  while (CH > 2){
    size_t need = fixedOff + (size_t)CH*(8*65536 + 524288) + 65536;
    if (need <= ws_size) break;
    CH >>= 1;
  }
  __bf16* Ht   = (__bf16*)alloc((size_t)CH*65536);
  __bf16* T1t  = (__bf16*)alloc((size_t)CH*65536);
  __bf16* T2t  = (__bf16*)alloc((size_t)CH*65536);
  __bf16* T3t  = (__bf16*)alloc((size_t)CH*65536);
  __bf16* KXnd = (__bf16*)alloc((size_t)CH*65536);
  __bf16* Hnd  = (__bf16*)alloc((size_t)CH*65536);
  __bf16* SXnd = (__bf16*)alloc((size_t)CH*65536);
  __bf16* Gnd  = (__bf16*)alloc((size_t)CH*65536);
  __bf16* Pt   = (__bf16*)alloc((size_t)CH*524288);

  const bool swz = (CH % 8) == 0;

  // preprocessing
  k_coe<<<1, 64, 0, stream>>>(temp, coe);
  k_cvt<<<1024, 256, 0, stream>>>(adj, adjb, 512*512);
  k_cvt<<<1024, 256, 0, stream>>>(Ksa, Ksab, 512*512);
  k_cvt_swz<<<1024, 256, 0, stream>>>(Vsa, Vsab);
  k_w1t<<<1, 256, 0, stream>>>(W1, W1t);
  k_wlt<<<dim3(512,2), 256, 0, stream>>>(Wl, Wlt);
  k_bsat<<<dim3(8,8), 256, 0, stream>>>(bsa, bsaTb);

  for (int s0 = 0; s0 < 128; s0 += CH){
    // embed both layouts
    k_embed2<<<dim3(CH,8), 256, 0, stream>>>(x + (size_t)s0*512, Wp, bp, Ht, Hnd);
    // Chebyshev (j-major); each gated: skipped entirely when its coefficients are all 0
    gbt<64,128,2,2,0,false><<<dim3(CH,4,1), 256, 0, stream>>>(Ht, 0, 512, adjb, 0, 512, nullptr, 0, T1t, 0, 512, 512, 0, 0, coe+1, 3);
    gbt<64,128,2,2,1,false><<<dim3(CH,4,1), 256, 0, stream>>>(T1t, 0, 512, adjb, 0, 512, Ht, 0, T2t, 0, 512, 512, 0, 0, coe+2, 2);
    gbt<64,128,2,2,1,false><<<dim3(CH,4,1), 256, 0, stream>>>(T2t, 0, 512, adjb, 0, 512, T1t, 0, T3t, 0, 512, 512, 0, 0, coe+3, 1);
    // KXnd[cs][m][d] = Ksa @ H
    gbt<64,64,2,2,0,false><<<dim3(8,1,CH), 256, 0, stream>>>(Ksab, 0, 512, Ht, 32768, 512,
                                                             nullptr, 0, KXnd, 32768, 64, 512, 0, 0, nullptr, 0);
    // Pt[cs][c][m] = tanh(KXnd*Hnd^T + bsaTb), XCD-swizzled, repack + col-swizzled store
    if (swz)
      gbt<128,128,2,2,2,true><<<dim3(16*CH), 256, 0, stream>>>(KXnd, 32768, 64, Hnd, 32768, 64,
                                                               bsaTb, 0, Pt, 262144, 512, 64, 4, 4, nullptr, 0);
    else
      gbt<128,128,2,2,2,false><<<dim3(4,4,CH), 256, 0, stream>>>(KXnd, 32768, 64, Hnd, 32768, 64,
                                                                 bsaTb, 0, Pt, 262144, 512, 64, 0, 0, nullptr, 0);
    // flash v8: SXnd = softmax(Vsa @ Pt^T) @ h
    if (swz)
      k_flash<true><<<dim3(8*CH), 256, 0, stream>>>(Vsab, Pt, Ht, SXnd);
    else
      k_flash<false><<<dim3(8,CH), 256, 0, stream>>>(Vsab, Pt, Ht, SXnd);
    // Gnd = cheby combo (zero terms skipped) + SXnd
    k_combo<<<dim3(CH,8), 256, 0, stream>>>(Ht, T1t, T2t, T3t, SXnd, coe, Gnd);
    // G2b = bf16(leaky(Gnd*W1t^T + b1))
    gbt<64,64,2,2,5,false><<<dim3(8,1,CH), 256, 0, stream>>>(Gnd, 32768, 64, W1t, 0, 64,
                                                             b1, 0, G2b + (size_t)s0*32768, 32768, 64, 64, 0, 0, nullptr, 0);
  }

  // final: part[z] = G2b[:, z*256:(z+1)*256] @ Wlt[:, z*256:(z+1)*256]^T
  gbt<128,128,2,2,3,false><<<dim3(1,1,128), 256, 0, stream>>>(G2b, 256, 32768, Wlt, 256, 32768,
                                                              nullptr, 0, part, 16384, 128, 256, 0, 0, nullptr, 0);
  // out = leaky(sum_z part + bl)
  k_final2<<<dim3(64), 256, 0, stream>>>(part, bl, out);
}

// Round 20
// 187.086 us; speedup vs baseline: 1.1001x; 1.1001x over previous
//
#include <hip/hip_runtime.h>
#include <math.h>

#define KORD 3
#ifndef M_PI
#define M_PI 3.14159265358979323846
#endif

typedef __attribute__((ext_vector_type(8))) __bf16 bf16x8;
typedef __attribute__((ext_vector_type(4))) float  f32x4;

__device__ __forceinline__ float leaky_(float v){ return v >= 0.f ? v : 0.01f*v; }

__device__ __forceinline__ float tanh_fast(float x){
  float xc = fminf(fmaxf(x, -10.f), 10.f);
  float t = __expf(2.f*xc);
  return (t - 1.f) * __builtin_amdgcn_rcpf(t + 1.f);
}

__device__ __forceinline__ f32x4 mfma16(bf16x8 a, bf16x8 b, f32x4 c){
  return __builtin_amdgcn_mfma_f32_16x16x32_bf16(a, b, c, 0, 0, 0);
}

// direct global->LDS DMA, 16B per lane (lds dest = wave-uniform base + lane*16)
__device__ __forceinline__ void gll16(const __bf16* g, __bf16* l){
  __builtin_amdgcn_global_load_lds(
      (__attribute__((address_space(1))) void*)(g),
      (__attribute__((address_space(3))) void*)(l), 16, 0, 0);
}

// ---------------- Chebyshev coefficients (flush |c|<1e-6 to exact 0) ----------------
__global__ void k_coe(const float* __restrict__ temp, float* __restrict__ coe){
  if (threadIdx.x == 0 && blockIdx.x == 0){
    for (int i = 0; i <= KORD; ++i){
      float acc = 0.f;
      for (int j = 0; j <= KORD; ++j){
        double th = ((double)(KORD - j) + 0.5) * M_PI / (double)(KORD + 1);
        float t = temp[j]; t = t > 0.f ? t : 0.f;
        acc += t * (float)cos((double)i * th);
      }
      acc *= 2.f / (float)(KORD + 1);
      if (i >= 1 && fabsf(acc) < 1e-6f) acc = 0.f;
      coe[i] = acc;
    }
  }
}

// ---------------- f32 -> bf16 convert ----------------
__global__ __launch_bounds__(256) void k_cvt(const float* __restrict__ in,
                                             __bf16* __restrict__ out, int n){
  int i = blockIdx.x*256 + threadIdx.x;
  if (i < n) out[i] = (__bf16)in[i];
}

// ---------------- f32 -> bf16 convert with per-64-col XOR swizzle ----------------
__global__ __launch_bounds__(256) void k_cvt_swz(const float* __restrict__ in,
                                                 __bf16* __restrict__ out){
  int i = blockIdx.x*256 + threadIdx.x;
  int r = i >> 9, c = i & 511;
  out[(size_t)r*512 + (c ^ ((r & 7) << 3))] = (__bf16)in[i];
}

// ---------------- W1t[e][d] = W1[d][e] (bf16) ----------------
__global__ __launch_bounds__(256) void k_w1t(const float* __restrict__ W1,
                                             __bf16* __restrict__ W1t){
  int t = threadIdx.x;
  for (int i = 0; i < 16; ++i){
    int e4 = i*256 + t;
    int e = e4 >> 6, d = e4 & 63;
    W1t[e*64 + d] = (__bf16)W1[d*64 + e];
  }
}

// ---------------- Wlt[o][k] = Wl[k][o] (bf16), Wl: [32768][128] ----------------
__global__ __launch_bounds__(256) void k_wlt(const float* __restrict__ Wl,
                                             __bf16* __restrict__ Wlt){
  __shared__ float Ls[64][65];
  int k0 = blockIdx.x*64, o0 = blockIdx.y*64;
  int t = threadIdx.x;
  for (int i = 0; i < 16; ++i){
    int e = i*256 + t; int r = e >> 6, c = e & 63;
    Ls[r][c] = Wl[(size_t)(k0 + r)*128 + o0 + c];
  }
  __syncthreads();
  for (int i = 0; i < 16; ++i){
    int e = i*256 + t; int r = e >> 6, c = e & 63;
    Wlt[(size_t)(o0 + r)*32768 + k0 + c] = (__bf16)Ls[c][r];
  }
}

// ---------------- bsaTb[c][m] = bf16(bsa[m][c]) ----------------
__global__ __launch_bounds__(256) void k_bsat(const float* __restrict__ bsa,
                                              __bf16* __restrict__ bsaTb){
  __shared__ float Ls[64][65];
  int n0 = blockIdx.x*64, m0 = blockIdx.y*64;
  int t = threadIdx.x;
  for (int i = 0; i < 16; ++i){
    int e = i*256 + t; int r = e >> 6, c = e & 63;
    Ls[r][c] = bsa[(size_t)(n0 + r)*512 + m0 + c];
  }
  __syncthreads();
  for (int i = 0; i < 16; ++i){
    int e = i*256 + t; int r = e >> 6, c = e & 63;
    bsaTb[(size_t)(m0 + r)*512 + n0 + c] = (__bf16)Ls[c][r];
  }
}

// ---------------- embed both layouts: Ht[j][n] and Hnd[cs][n][d] ----------------
__global__ __launch_bounds__(256) void k_embed2(const float* __restrict__ x,
    const float* __restrict__ Wp, const float* __restrict__ bp,
    __bf16* __restrict__ Ht, __bf16* __restrict__ Hnd){
  __shared__ float Ls[64][65];
  int cs = blockIdx.x, n0 = blockIdx.y*64;
  int t = threadIdx.x;
  for (int i = 0; i < 16; ++i){
    int e = i*256 + t; int d = e >> 6, nn = e & 63;
    float v = x[cs*512 + n0 + nn]*Wp[d] + bp[d];
    Ls[d][nn] = v;
    Ht[(size_t)(cs*64 + d)*512 + n0 + nn] = (__bf16)v;
  }
  __syncthreads();
  for (int i = 0; i < 16; ++i){
    int e = i*256 + t; int nn = e >> 6, d = e & 63;
    Hnd[((size_t)cs*512 + n0 + nn)*64 + d] = (__bf16)Ls[d][nn];
  }
}

// ---------------- combo: Gnd[cs][n][d] = cheby-combo + SXnd (zero-coe terms skipped) ----------------
__global__ __launch_bounds__(256) void k_combo(const __bf16* __restrict__ Ht,
    const __bf16* __restrict__ T1t, const __bf16* __restrict__ T2t,
    const __bf16* __restrict__ T3t, const __bf16* __restrict__ SXnd,
    const float* __restrict__ coe, __bf16* __restrict__ Gnd){
  __shared__ float Ls[64][65];
  int cs = blockIdx.x, n0 = blockIdx.y*64;
  int t = threadIdx.x;
  float c0 = coe[0]*0.5f, c1 = coe[1], c2 = coe[2], c3 = coe[3];
  for (int i = 0; i < 16; ++i){
    int e = i*256 + t; int d = e >> 6, nn = e & 63;
    size_t idx = (size_t)(cs*64 + d)*512 + n0 + nn;
    float v = c0*(float)Ht[idx];
    if (c1 != 0.f) v += c1*(float)T1t[idx];
    if (c2 != 0.f) v += c2*(float)T2t[idx];
    if (c3 != 0.f) v += c3*(float)T3t[idx];
    Ls[d][nn] = v;
  }
  __syncthreads();
  for (int i = 0; i < 16; ++i){
    int e = i*256 + t; int nn = e >> 6, d = e & 63;
    size_t oidx = ((size_t)cs*512 + n0 + nn)*64 + d;
    Gnd[oidx] = (__bf16)(Ls[d][nn] + (float)SXnd[oidx]);
  }
}

// ---------------- MFMA GEMM: C[z] = A[z] * B[z]^T (+epilogue) ----------------
// EPI: 0 bf16 out; 1 bf16 2v-Z; 2 bf16 tanh_fast(v+Eb16[row*512+col]) REPACK + col-swizzle;
//      3 f32 out; 5 bf16 leaky(v+Ef[col])
template<int BM, int BN, int WM, int WN, int EPI, bool SWZ>
__global__ __launch_bounds__(256) void gbt(
    const __bf16* __restrict__ A, size_t aB, int lda,
    const __bf16* __restrict__ B, size_t bB, int ldb,
    const void*  __restrict__ E, size_t eB,
    void* __restrict__ C, size_t cB, int ldc, int K, int gx, int gy,
    const float* __restrict__ gate, int gateCnt){
  if (gate){
    bool anyNZ = false;
    for (int i = 0; i < gateCnt; ++i) anyNZ |= (gate[i] != 0.f);
    if (!anyNZ) return;
  }
  constexpr int WTM = BM/WM, WTN = BN/WN;
  constexpr int FM = WTM/16, FN = WTN/16;
  constexpr int LDK = 72;
  constexpr bool RPK = (EPI == 2 && BM == 128 && BN == 128);
  __shared__ __bf16 SMEM[BM*LDK + BN*LDK];
  __bf16* As = SMEM;
  __bf16* Bs = SMEM + BM*LDK;
  const int tid = threadIdx.x;
  const int wave = tid >> 6, lane = tid & 63;
  const int wm = wave % WM, wn = wave / WM;
  int bx, by, bz;
  if (SWZ){
    int id = blockIdx.x;
    int xcd = id & 7, j = id >> 3;
    int tiles = gx*gy;
    int tile = j % tiles, sin = j / tiles;
    bz = xcd + 8*sin; bx = tile % gx; by = tile / gx;
  } else { bx = blockIdx.x; by = blockIdx.y; bz = blockIdx.z; }
  const int m0 = bx*BM, n0 = by*BN;
  const __bf16* Ab = A + (size_t)bz*aB + (size_t)m0*lda;
  const __bf16* Bb = B + (size_t)bz*bB + (size_t)n0*ldb;
  f32x4 acc[FM][FN] = {};
  for (int k0 = 0; k0 < K; k0 += 64){
    __syncthreads();
    constexpr int AIT = BM*64/(256*8);
#pragma unroll
    for (int i = 0; i < AIT; ++i){
      int e = i*256 + tid; int r = e >> 3, c = (e & 7)*8;
      *(float4*)&As[r*LDK + c] = *(const float4*)&Ab[(size_t)r*lda + k0 + c];
    }
    constexpr int BIT = BN*64/(256*8);
#pragma unroll
    for (int i = 0; i < BIT; ++i){
      int e = i*256 + tid; int r = e >> 3, c = (e & 7)*8;
      *(float4*)&Bs[r*LDK + c] = *(const float4*)&Bb[(size_t)r*ldb + k0 + c];
    }
    __syncthreads();
#pragma unroll
    for (int ks = 0; ks < 2; ++ks){
      bf16x8 af[FM], bfr[FN];
      const int ko = ks*32 + (lane >> 4)*8;
#pragma unroll
      for (int i = 0; i < FM; ++i)
        af[i] = *(const bf16x8*)&As[(wm*WTM + i*16 + (lane & 15))*LDK + ko];
#pragma unroll
      for (int j = 0; j < FN; ++j)
        bfr[j] = *(const bf16x8*)&Bs[(wn*WTN + j*16 + (lane & 15))*LDK + ko];
#pragma unroll
      for (int i = 0; i < FM; ++i)
#pragma unroll
        for (int j = 0; j < FN; ++j)
          acc[i][j] = mfma16(af[i], bfr[j], acc[i][j]);
    }
  }
  const int lr = (lane >> 4)*4, lc = lane & 15;
  __bf16* Cb = (__bf16*)C + (size_t)bz*cB;
  if constexpr (RPK){
    const __bf16* Eb = (const __bf16*)E;
    __syncthreads();
    __bf16* R = SMEM;  // 128*136*2B = 34816
#pragma unroll
    for (int i = 0; i < FM; ++i)
#pragma unroll
      for (int j = 0; j < FN; ++j)
#pragma unroll
        for (int r = 0; r < 4; ++r){
          int row = wm*64 + i*16 + lr + r;
          int col = wn*64 + j*16 + lc;
          float v = tanh_fast(acc[i][j][r] + (float)Eb[(size_t)(m0 + row)*512 + (n0 + col)]);
          R[row*136 + col] = (__bf16)v;
        }
    __syncthreads();
#pragma unroll
    for (int it = 0; it < 8; ++it){
      int q = it*256 + tid; int row = q >> 4, ch = q & 15;
      *(bf16x8*)&Cb[(size_t)(m0 + row)*ldc + (n0 + ((ch*8) ^ ((row & 7) << 3)))] =
          *(const bf16x8*)&R[row*136 + ch*8];
    }
    return;
  }
  float*  Cf = (float*)C  + (size_t)bz*cB;
  const __bf16* Zb = (const __bf16*)E + (size_t)bz*eB;
  const float*  Ef = (const float*)E;
  const __bf16* Eb = (const __bf16*)E;
#pragma unroll
  for (int i = 0; i < FM; ++i){
    int row = m0 + wm*WTM + i*16 + lr;
#pragma unroll
    for (int j = 0; j < FN; ++j){
      int col = n0 + wn*WTN + j*16 + lc;
#pragma unroll
      for (int r = 0; r < 4; ++r){
        float v = acc[i][j][r];
        size_t idx = (size_t)(row + r)*ldc + col;
        if (EPI == 0){ Cb[idx] = (__bf16)v; }
        else if (EPI == 1){ Cb[idx] = (__bf16)(2.f*v - (float)Zb[idx]); }
        else if (EPI == 2){ Cb[(size_t)(row + r)*ldc + (col ^ (((row + r) & 7) << 3))] =
                              (__bf16)tanh_fast(v + (float)Eb[(size_t)(row + r)*512 + col]); }
        else if (EPI == 3){ Cf[idx] = v; }
        else if (EPI == 5){ float tt = v + Ef[col]; Cb[idx] = (__bf16)(tt >= 0.f ? tt : 0.01f*tt); }
      }
    }
  }
}

// ---------------- flash v7: triple-buffered gload_lds + counted vmcnt + raw barriers ----------------
// Vsab/Pt col-swizzled; Ht plain (PV h-frags loaded to regs per c0).
template<bool SWZ>
__global__ __launch_bounds__(256) void k_flash(
    const __bf16* __restrict__ Vsab,  // [512][512] swizzled
    const __bf16* __restrict__ Pt,    // [z][512(c)][512(m)] swizzled
    const __bf16* __restrict__ Ht,    // [z*64(d)][512(m)] plain
    __bf16* __restrict__ SXnd){       // [z][512(n')][64(d)]
  __shared__ __bf16 VaL[3][4096];     // [64][64] linear, triple
  __shared__ __bf16 PbL[3][4096];
  __shared__ __bf16 Ps[64*72];
  __shared__ float rs2[2][64];
  const int tid = threadIdx.x, wave = tid >> 6, lane = tid & 63;
  const int wm = wave & 1, wn = wave >> 1;
  const int lr = (lane >> 4)*4, lc = lane & 15;
  int np0, z;
  if (SWZ){
    int id = blockIdx.x;
    int xcd = id & 7, j = id >> 3;
    int tile = j & 7, sin = j >> 3;
    z = xcd + 8*sin; np0 = tile*64;
  } else { np0 = blockIdx.x*64; z = blockIdx.y; }
  const __bf16* Vb = Vsab + (size_t)np0*512;
  const __bf16* Pz = Pt + (size_t)z*262144;
  const __bf16* Hz = Ht + (size_t)z*32768;
  const int srow = lane >> 3;
  const int scol = (lane & 7)*8;
  auto stageVP = [&](int buf, int c0, int k0){
#pragma unroll
    for (int rr = 0; rr < 2; ++rr){
      int rb = (rr*4 + wave)*8;
      gll16(Vb + (size_t)(rb + srow)*512 + k0 + scol, &VaL[buf][(rr*4 + wave)*512]);
      gll16(Pz + (size_t)(c0 + rb + srow)*512 + k0 + scol, &PbL[buf][(rr*4 + wave)*512]);
    }
  };
  const int kx = (lc & 7) << 3;
  f32x4 acc_sx[2][2] = {};
  float rowp[8] = {};
  // prologue: 2 tiles in flight
  stageVP(0, 0, 0);
  stageVP(1, 0, 64);
  int cur = 0;
  for (int c0i = 0; c0i < 8; ++c0i){
    const int c0 = c0i*64;
    f32x4 acc_s[2][2] = {};
#pragma unroll
    for (int k0i = 0; k0i < 8; ++k0i){
      // wait for tile cur (staged 2 iters ago); never drain to 0 except very last tile
      if (k0i == 7){
        if (c0i == 7) asm volatile("s_waitcnt vmcnt(0)" ::: "memory");
        else          asm volatile("s_waitcnt vmcnt(4)" ::: "memory");
      } else {
        asm volatile("s_waitcnt vmcnt(4)" ::: "memory");
      }
      __builtin_amdgcn_s_barrier();
      const __bf16* Vc = VaL[cur];
      const __bf16* Pc = PbL[cur];
#pragma unroll
      for (int ks = 0; ks < 2; ++ks){
        const int kox = (ks*32 + (lane >> 4)*8) ^ kx;
        bf16x8 a0 = *(const bf16x8*)&Vc[(wm*32 +  0 + lc)*64 + kox];
        bf16x8 a1 = *(const bf16x8*)&Vc[(wm*32 + 16 + lc)*64 + kox];
        bf16x8 b0 = *(const bf16x8*)&Pc[(wn*32 +  0 + lc)*64 + kox];
        bf16x8 b1 = *(const bf16x8*)&Pc[(wn*32 + 16 + lc)*64 + kox];
        acc_s[0][0] = mfma16(a0, b0, acc_s[0][0]);
        acc_s[0][1] = mfma16(a0, b1, acc_s[0][1]);
        acc_s[1][0] = mfma16(a1, b0, acc_s[1][0]);
        acc_s[1][1] = mfma16(a1, b1, acc_s[1][1]);
      }
      // issue stage for tile t+2 (writes buffer consumed at iter t-1; all waves past barrier(t))
      int nt = c0i*8 + k0i + 2;
      if (nt < 64){
        int bufn = cur + 2; if (bufn >= 3) bufn -= 3;
        stageVP(bufn, (nt >> 3) << 6, (nt & 7) << 6);
      }
      cur = (cur == 2) ? 0 : cur + 1;
    }
    // ---- epilogue for this c0 ----
    // exp + rowsum partials -> Ps
#pragma unroll
    for (int i = 0; i < 2; ++i)
#pragma unroll
      for (int j = 0; j < 2; ++j)
#pragma unroll
        for (int rr = 0; rr < 4; ++rr){
          float e = __expf(fminf(acc_s[i][j][rr], 30.f));
          rowp[i*4 + rr] += e;
          Ps[(wm*32 + i*16 + lr + rr)*72 + wn*32 + j*16 + lc] = (__bf16)e;
        }
    // h-fragments for PV straight from global (plain Ht); compiler inserts its own waits
    bf16x8 h0k[2], h1k[2];
#pragma unroll
    for (int ks = 0; ks < 2; ++ks){
      const int ko = ks*32 + (lane >> 4)*8;
      h0k[ks] = *(const bf16x8*)&Hz[(size_t)(wn*32 +  0 + lc)*512 + c0 + ko];
      h1k[ks] = *(const bf16x8*)&Hz[(size_t)(wn*32 + 16 + lc)*512 + c0 + ko];
    }
    asm volatile("s_waitcnt lgkmcnt(0)" ::: "memory");
    __builtin_amdgcn_s_barrier();
    // PV: acc_sx[n'][d] += expS @ h
#pragma unroll
    for (int ks = 0; ks < 2; ++ks){
      const int ko = ks*32 + (lane >> 4)*8;
      bf16x8 p0 = *(const bf16x8*)&Ps[(wm*32 +  0 + lc)*72 + ko];
      bf16x8 p1 = *(const bf16x8*)&Ps[(wm*32 + 16 + lc)*72 + ko];
      acc_sx[0][0] = mfma16(p0, h0k[ks], acc_sx[0][0]);
      acc_sx[0][1] = mfma16(p0, h1k[ks], acc_sx[0][1]);
      acc_sx[1][0] = mfma16(p1, h0k[ks], acc_sx[1][0]);
      acc_sx[1][1] = mfma16(p1, h1k[ks], acc_sx[1][1]);
    }
  }
  // rowsum reduce (16-lane groups), combine wn waves via LDS
#pragma unroll
  for (int s = 0; s < 8; ++s){
    float v = rowp[s];
    v += __shfl_xor(v, 1, 64); v += __shfl_xor(v, 2, 64);
    v += __shfl_xor(v, 4, 64); v += __shfl_xor(v, 8, 64);
    rowp[s] = v;
  }
  __syncthreads();
  if ((lane & 15) == 0){
#pragma unroll
    for (int i = 0; i < 2; ++i)
#pragma unroll
      for (int rr = 0; rr < 4; ++rr)
        rs2[wn][wm*32 + i*16 + lr + rr] = rowp[i*4 + rr];
  }
  __syncthreads();
#pragma unroll
  for (int i = 0; i < 2; ++i)
#pragma unroll
    for (int rr = 0; rr < 4; ++rr){
      int row = wm*32 + i*16 + lr + rr;
      float inv = __builtin_amdgcn_rcpf(rs2[0][row] + rs2[1][row]);
#pragma unroll
      for (int j = 0; j < 2; ++j){
        int col = wn*32 + j*16 + lc;
        SXnd[((size_t)z*512 + np0 + row)*64 + col] = (__bf16)(acc_sx[i][j][rr]*inv);
      }
    }
}

// ---------------- reduce 128 K-partials + bias + leaky ----------------
__global__ __launch_bounds__(256) void k_final2(
    const float* __restrict__ part, const float* __restrict__ bl,
    float* __restrict__ out){
  int idx = blockIdx.x*256 + threadIdx.x;
  int o = idx & 127;
  float acc = bl[o];
#pragma unroll 8
  for (int p = 0; p < 128; ++p) acc += part[(size_t)p*16384 + idx];
  out[idx] = leaky_(acc);
}

extern "C" void kernel_launch(void* const* d_in, const int* in_sizes, int n_in,
                              void* d_out, int out_size, void* d_ws, size_t ws_size,
                              hipStream_t stream){
  const float* x    = (const float*)d_in[0];
  const float* adj  = (const float*)d_in[1];
  const float* Wp   = (const float*)d_in[2];
  const float* bp   = (const float*)d_in[3];
  const float* Ksa  = (const float*)d_in[4];
  const float* Vsa  = (const float*)d_in[5];
  const float* bsa  = (const float*)d_in[6];
  const float* temp = (const float*)d_in[7];
  const float* W1   = (const float*)d_in[8];
  const float* b1   = (const float*)d_in[9];
  const float* Wl   = (const float*)d_in[10];
  const float* bl   = (const float*)d_in[11];
  float* out = (float*)d_out;

  // ---- workspace carve-up (bytes), chunk-adaptive ----
  char* ws = (char*)d_ws;
  size_t off = 0;
  auto alloc = [&](size_t bytes){ void* p = ws + off; off += (bytes + 255) & ~(size_t)255; return p; };
  float*  coe  = (float*)alloc(64);
  __bf16* G2b  = (__bf16*)alloc((size_t)128*32768*2);   // 8.4 MB
  __bf16* Wlt  = (__bf16*)alloc((size_t)128*32768*2);   // 8.4 MB
  float*  part = (float*)alloc((size_t)128*16384*4);    // 8.4 MB
  __bf16* bsaTb= (__bf16*)alloc((size_t)512*512*2);     // 0.5 MB bf16
  __bf16* adjb = (__bf16*)alloc((size_t)512*512*2);
  __bf16* Ksab = (__bf16*)alloc((size_t)512*512*2);
  __bf16* Vsab = (__bf16*)alloc((size_t)512*512*2);
  __bf16* W1t  = (__bf16*)alloc((size_t)64*64*2);
  const size_t fixedOff = off;

  // per-slice: 8 bf16 [64x512]-sized bufs (64KB each) + Pt (512KB)
  int CH = 128;
  while (CH > 2){
    size_t need = fixedOff + (size_t)CH*(8*65536 + 524288) + 65536;
    if (need <= ws_size) break;
    CH >>= 1;
  }
  __bf16* Ht   = (__bf16*)alloc((size_t)CH*65536);
  __bf16* T1t  = (__bf16*)alloc((size_t)CH*65536);
  __bf16* T2t  = (__bf16*)alloc((size_t)CH*65536);
  __bf16* T3t  = (__bf16*)alloc((size_t)CH*65536);
  __bf16* KXnd = (__bf16*)alloc((size_t)CH*65536);
  __bf16* Hnd  = (__bf16*)alloc((size_t)CH*65536);
  __bf16* SXnd = (__bf16*)alloc((size_t)CH*65536);
  __bf16* Gnd  = (__bf16*)alloc((size_t)CH*65536);
  __bf16* Pt   = (__bf16*)alloc((size_t)CH*524288);

  const bool swz = (CH % 8) == 0;

  // preprocessing
  k_coe<<<1, 64, 0, stream>>>(temp, coe);
  k_cvt<<<1024, 256, 0, stream>>>(adj, adjb, 512*512);
  k_cvt<<<1024, 256, 0, stream>>>(Ksa, Ksab, 512*512);
  k_cvt_swz<<<1024, 256, 0, stream>>>(Vsa, Vsab);
  k_w1t<<<1, 256, 0, stream>>>(W1, W1t);
  k_wlt<<<dim3(512,2), 256, 0, stream>>>(Wl, Wlt);
  k_bsat<<<dim3(8,8), 256, 0, stream>>>(bsa, bsaTb);

  for (int s0 = 0; s0 < 128; s0 += CH){
    // embed both layouts
    k_embed2<<<dim3(CH,8), 256, 0, stream>>>(x + (size_t)s0*512, Wp, bp, Ht, Hnd);
    // Chebyshev (j-major); each gated: skipped entirely when its coefficients are all 0
    gbt<64,128,2,2,0,false><<<dim3(CH,4,1), 256, 0, stream>>>(Ht, 0, 512, adjb, 0, 512, nullptr, 0, T1t, 0, 512, 512, 0, 0, coe+1, 3);
    gbt<64,128,2,2,1,false><<<dim3(CH,4,1), 256, 0, stream>>>(T1t, 0, 512, adjb, 0, 512, Ht, 0, T2t, 0, 512, 512, 0, 0, coe+2, 2);
    gbt<64,128,2,2,1,false><<<dim3(CH,4,1), 256, 0, stream>>>(T2t, 0, 512, adjb, 0, 512, T1t, 0, T3t, 0, 512, 512, 0, 0, coe+3, 1);
    // KXnd[cs][m][d] = Ksa @ H
    gbt<64,64,2,2,0,false><<<dim3(8,1,CH), 256, 0, stream>>>(Ksab, 0, 512, Ht, 32768, 512,
                                                             nullptr, 0, KXnd, 32768, 64, 512, 0, 0, nullptr, 0);
    // Pt[cs][c][m] = tanh(KXnd*Hnd^T + bsaTb), XCD-swizzled, repack + col-swizzled store
    if (swz)
      gbt<128,128,2,2,2,true><<<dim3(16*CH), 256, 0, stream>>>(KXnd, 32768, 64, Hnd, 32768, 64,
                                                               bsaTb, 0, Pt, 262144, 512, 64, 4, 4, nullptr, 0);
    else
      gbt<128,128,2,2,2,false><<<dim3(4,4,CH), 256, 0, stream>>>(KXnd, 32768, 64, Hnd, 32768, 64,
                                                                 bsaTb, 0, Pt, 262144, 512, 64, 0, 0, nullptr, 0);
    // flash v7: SXnd = softmax(Vsa @ Pt^T) @ h
    if (swz)
      k_flash<true><<<dim3(8*CH), 256, 0, stream>>>(Vsab, Pt, Ht, SXnd);
    else
      k_flash<false><<<dim3(8,CH), 256, 0, stream>>>(Vsab, Pt, Ht, SXnd);
    // Gnd = cheby combo (zero terms skipped) + SXnd
    k_combo<<<dim3(CH,8), 256, 0, stream>>>(Ht, T1t, T2t, T3t, SXnd, coe, Gnd);
    // G2b = bf16(leaky(Gnd*W1t^T + b1))
    gbt<64,64,2,2,5,false><<<dim3(8,1,CH), 256, 0, stream>>>(Gnd, 32768, 64, W1t, 0, 64,
                                                             b1, 0, G2b + (size_t)s0*32768, 32768, 64, 64, 0, 0, nullptr, 0);
  }

  // final: part[z] = G2b[:, z*256:(z+1)*256] @ Wlt[:, z*256:(z+1)*256]^T
  gbt<128,128,2,2,3,false><<<dim3(1,1,128), 256, 0, stream>>>(G2b, 256, 32768, Wlt, 256, 32768,
                                                              nullptr, 0, part, 16384, 128, 256, 0, 0, nullptr, 0);
  // out = leaky(sum_z part + bl)
  k_final2<<<dim3(64), 256, 0, stream>>>(part, bl, out);
}